// Round 1
// baseline (2019.901 us; speedup 1.0000x reference)
//
#include <hip/hip_runtime.h>
#include <hip/hip_bf16.h>

// Deformable1DFeatureAggregator on MI355X (gfx950)
// B=2, C=256, H=128, W=256, P=9, G=8, GC=32
//
// Pipeline (3 kernels, each: 32-pixel tile per 256-thread block, 2048 blocks):
//   K1: LN(feats1) -> [Ww|Wk] proj -> softmax over P -> wts (ws, fp32), kp (d_out tail)
//   K2: LN(feats2) -> value proj (C x C) -> value (ws, bf16)
//   K3: bilinear gather + group-weighted point sum -> out proj (C x C) -> out (d_out head)
//
// ws layout: [0, 18874368) wts fp32 (B*HW*P*G); [18874368, +33554432) value bf16 (B*HW*C)

constexpr int B = 2, C = 256, H = 128, W = 256;
constexpr int HW = H * W;            // 32768
constexpr int P = 9, G = 8;
constexpr int GP = G * P;            // 72
constexpr int PIX = 32;              // pixels per block
constexpr int NPIX = B * HW;         // 65536
constexpr int NBLK = NPIX / PIX;     // 2048
constexpr size_t WTS_FLOATS = (size_t)B * HW * P * G;   // 4,718,592
constexpr size_t VAL_OFF_BYTES = WTS_FLOATS * 4;        // 18,874,368

// ---------------------------------------------------------------------------
// K1: LN(feats1) + weight/key projections + softmax + keypoint output
// ---------------------------------------------------------------------------
__global__ __launch_bounds__(256) void k1_ln1_proj(
    const float* __restrict__ feats1,
    const float* __restrict__ anchor,
    const float* __restrict__ g1, const float* __restrict__ b1,
    const float* __restrict__ Ww, const float* __restrict__ bw,
    const float* __restrict__ Wk, const float* __restrict__ bk,
    float* __restrict__ wts, float* __restrict__ kp_out)
{
    __shared__ float X[PIX][C + 1];        // 32 x 257 fp32, +1 pad vs 32-bank conflicts
    __shared__ float red[2][8][PIX];
    __shared__ float meanA[PIX], rstdA[PIX];
    __shared__ float L[PIX][73];           // logits, stride 73 (gcd(9,32)=1) for softmax reads

    const int t = threadIdx.x;
    const int p = t & 31;                  // pixel within tile
    const int part = t >> 5;               // 0..7
    const int gpix0 = blockIdx.x * PIX;    // global pixel base (b*HW + n0)
    const int b = gpix0 >> 15;             // HW = 32768
    const int n0 = gpix0 & (HW - 1);
    const float* Fb = feats1 + (size_t)b * C * HW;

    // coalesced load (b,c,hw) -> LDS transpose (pix, c)
    #pragma unroll
    for (int i = 0; i < 32; ++i) {
        int c = i * 8 + part;
        X[p][c] = Fb[(size_t)c * HW + n0 + p];
    }
    __syncthreads();

    // LayerNorm over channels, per pixel (8 partial threads per pixel)
    float s = 0.f, ss = 0.f;
    #pragma unroll
    for (int i = 0; i < 32; ++i) {
        float v = X[p][part * 32 + i];
        s += v; ss += v * v;
    }
    red[0][part][p] = s;
    red[1][part][p] = ss;
    __syncthreads();
    if (part == 0) {
        float s2 = 0.f, ss2 = 0.f;
        #pragma unroll
        for (int k = 0; k < 8; ++k) { s2 += red[0][k][p]; ss2 += red[1][k][p]; }
        float mean = s2 * (1.f / C);
        float var  = ss2 * (1.f / C) - mean * mean;
        meanA[p] = mean;
        rstdA[p] = rsqrtf(var + 1e-5f);
    }
    __syncthreads();
    {
        float mean = meanA[p], rstd = rstdA[p];
        #pragma unroll
        for (int i = 0; i < 32; ++i) {
            int c = part * 32 + i;
            X[p][c] = (X[p][c] - mean) * rstd * g1[c] + b1[c];
        }
    }
    __syncthreads();

    const int n = n0 + p;
    const size_t pixg = (size_t)b * HW + n;
    const float ax = anchor[pixg * 2 + 0];
    const float ay = anchor[pixg * 2 + 1];

    // 81 dot products per pixel: j<72 -> logits (layout pt*G+g), j>=72 -> x-offset pt
    for (int j = part; j < 81; j += 8) {
        if (j < 72) {
            float acc = bw[j];
            #pragma unroll 4
            for (int c = 0; c < C; ++c) acc += X[p][c] * Ww[c * GP + j];
            L[p][j] = acc;
        } else {
            int pt = j - 72;
            float acc = bk[pt];
            #pragma unroll 4
            for (int c = 0; c < C; ++c) acc += X[p][c] * Wk[c * P + pt];
            size_t o = (pixg * P + pt) * 2;
            kp_out[o]     = ax + acc;
            kp_out[o + 1] = ay;
        }
    }
    __syncthreads();

    // softmax over P per (pixel, group): thread -> (p, g=part)
    {
        const int g = part;
        float m = -1e30f;
        #pragma unroll
        for (int pt = 0; pt < P; ++pt) m = fmaxf(m, L[p][pt * G + g]);
        float e[P];
        float sum = 0.f;
        #pragma unroll
        for (int pt = 0; pt < P; ++pt) { e[pt] = __expf(L[p][pt * G + g] - m); sum += e[pt]; }
        float inv = 1.f / sum;
        float* wbase = wts + pixg * GP + g;
        #pragma unroll
        for (int pt = 0; pt < P; ++pt) wbase[pt * G] = e[pt] * inv;
    }
}

// ---------------------------------------------------------------------------
// K2: LN(feats2) + value projection (C x C), store bf16
// ---------------------------------------------------------------------------
__global__ __launch_bounds__(256) void k2_ln2_value(
    const float* __restrict__ feats2,
    const float* __restrict__ g2, const float* __restrict__ b2,
    const float* __restrict__ Wv, const float* __restrict__ bv,
    __hip_bfloat16* __restrict__ val)
{
    __shared__ float X[PIX][C + 1];
    __shared__ float red[2][8][PIX];
    __shared__ float meanA[PIX], rstdA[PIX];

    const int t = threadIdx.x;
    const int p = t & 31;
    const int part = t >> 5;
    const int gpix0 = blockIdx.x * PIX;
    const int b = gpix0 >> 15;
    const int n0 = gpix0 & (HW - 1);
    const float* Fb = feats2 + (size_t)b * C * HW;

    #pragma unroll
    for (int i = 0; i < 32; ++i) {
        int c = i * 8 + part;
        X[p][c] = Fb[(size_t)c * HW + n0 + p];
    }
    __syncthreads();

    float s = 0.f, ss = 0.f;
    #pragma unroll
    for (int i = 0; i < 32; ++i) {
        float v = X[p][part * 32 + i];
        s += v; ss += v * v;
    }
    red[0][part][p] = s;
    red[1][part][p] = ss;
    __syncthreads();
    if (part == 0) {
        float s2 = 0.f, ss2 = 0.f;
        #pragma unroll
        for (int k = 0; k < 8; ++k) { s2 += red[0][k][p]; ss2 += red[1][k][p]; }
        float mean = s2 * (1.f / C);
        float var  = ss2 * (1.f / C) - mean * mean;
        meanA[p] = mean;
        rstdA[p] = rsqrtf(var + 1e-5f);
    }
    __syncthreads();
    {
        float mean = meanA[p], rstd = rstdA[p];
        #pragma unroll
        for (int i = 0; i < 32; ++i) {
            int c = part * 32 + i;
            X[p][c] = (X[p][c] - mean) * rstd * g2[c] + b2[c];
        }
    }
    __syncthreads();

    // value[n][j], j = part*32 .. part*32+31 per thread (register tile)
    const int j0 = part * 32;
    float acc[32];
    #pragma unroll
    for (int i = 0; i < 32; ++i) acc[i] = bv[j0 + i];

    for (int c = 0; c < C; ++c) {
        float x = X[p][c];
        const float4* row = (const float4*)(Wv + (size_t)c * C + j0);
        #pragma unroll
        for (int i4 = 0; i4 < 8; ++i4) {
            float4 w4 = row[i4];
            acc[i4 * 4 + 0] += x * w4.x;
            acc[i4 * 4 + 1] += x * w4.y;
            acc[i4 * 4 + 2] += x * w4.z;
            acc[i4 * 4 + 3] += x * w4.w;
        }
    }

    __hip_bfloat16* vrow = val + ((size_t)gpix0 + p) * C + j0;
    #pragma unroll
    for (int i = 0; i < 16; ++i) {
        __hip_bfloat162 h2;
        h2.x = __float2bfloat16(acc[2 * i]);
        h2.y = __float2bfloat16(acc[2 * i + 1]);
        *((__hip_bfloat162*)(vrow + 2 * i)) = h2;
    }
}

// ---------------------------------------------------------------------------
// K3: bilinear gather + group-weighted sum over points + output projection
// ---------------------------------------------------------------------------
__global__ __launch_bounds__(256) void k3_gather_out(
    const float* __restrict__ wts,
    const float* __restrict__ kp,
    const __hip_bfloat16* __restrict__ val,
    const float* __restrict__ Wo, const float* __restrict__ bo,
    float* __restrict__ out)
{
    __shared__ float A[PIX][C + 1];

    const int t = threadIdx.x;
    const int gpix0 = blockIdx.x * PIX;
    const int b = gpix0 >> 15;
    const int n0 = gpix0 & (HW - 1);
    const int g = t >> 5;                          // channel group of this thread's channel
    const __hip_bfloat16* vb = val + (size_t)b * HW * C;

    // phase 1: thread t = channel; loop pixels; 9 pts x 4 corners, coalesced 512B rows
    for (int px = 0; px < PIX; ++px) {
        const size_t pixg = (size_t)gpix0 + px;
        const float* kprow = kp + pixg * (size_t)(P * 2);
        const float* wrow  = wts + pixg * (size_t)GP + g;
        float ay  = kprow[1];
        float yf  = ay * (float)H - 0.5f;
        float y0f = floorf(yf);
        float wy  = yf - y0f;
        int   y0  = (int)y0f;
        bool  vy0 = (unsigned)y0 < (unsigned)H;
        bool  vy1 = (unsigned)(y0 + 1) < (unsigned)H;
        int   y0c = min(max(y0, 0), H - 1);
        int   y1c = min(max(y0 + 1, 0), H - 1);

        float acc = 0.f;
        #pragma unroll
        for (int pt = 0; pt < P; ++pt) {
            float kx  = kprow[pt * 2];
            float w   = wrow[pt * G];
            float xf  = kx * (float)W - 0.5f;
            float x0f = floorf(xf);
            float wx  = xf - x0f;
            int   x0  = (int)x0f;
            bool  vx0 = (unsigned)x0 < (unsigned)W;
            bool  vx1 = (unsigned)(x0 + 1) < (unsigned)W;
            int   x0c = min(max(x0, 0), W - 1);
            int   x1c = min(max(x0 + 1, 0), W - 1);

            float v00 = (vy0 && vx0) ? __bfloat162float(vb[((size_t)y0c * W + x0c) * C + t]) : 0.f;
            float v01 = (vy0 && vx1) ? __bfloat162float(vb[((size_t)y0c * W + x1c) * C + t]) : 0.f;
            float v10 = (vy1 && vx0) ? __bfloat162float(vb[((size_t)y1c * W + x0c) * C + t]) : 0.f;
            float v11 = (vy1 && vx1) ? __bfloat162float(vb[((size_t)y1c * W + x1c) * C + t]) : 0.f;

            float top = v00 + (v01 - v00) * wx;
            float bot = v10 + (v11 - v10) * wx;
            acc += w * (top + (bot - top) * wy);
        }
        A[px][t] = acc;
    }
    __syncthreads();

    // phase 2: out proj, register tile of 32 channels per thread
    const int p = t & 31;
    const int part = t >> 5;
    const int j0 = part * 32;
    float acc2[32];
    #pragma unroll
    for (int i = 0; i < 32; ++i) acc2[i] = bo[j0 + i];

    for (int c = 0; c < C; ++c) {
        float x = A[p][c];
        const float4* row = (const float4*)(Wo + (size_t)c * C + j0);
        #pragma unroll
        for (int i4 = 0; i4 < 8; ++i4) {
            float4 w4 = row[i4];
            acc2[i4 * 4 + 0] += x * w4.x;
            acc2[i4 * 4 + 1] += x * w4.y;
            acc2[i4 * 4 + 2] += x * w4.z;
            acc2[i4 * 4 + 3] += x * w4.w;
        }
    }

    // out layout (b, c, hw): for fixed j, 32 consecutive pixels -> 128B segments
    float* ob = out + (size_t)b * C * HW + n0 + p;
    #pragma unroll
    for (int i = 0; i < 32; ++i) {
        ob[(size_t)(j0 + i) * HW] = acc2[i];
    }
}

// ---------------------------------------------------------------------------
extern "C" void kernel_launch(void* const* d_in, const int* in_sizes, int n_in,
                              void* d_out, int out_size, void* d_ws, size_t ws_size,
                              hipStream_t stream)
{
    const float* feats1 = (const float*)d_in[0];
    const float* feats2 = (const float*)d_in[1];
    const float* anchor = (const float*)d_in[2];
    const float* n1g    = (const float*)d_in[3];
    const float* n1b    = (const float*)d_in[4];
    const float* n2g    = (const float*)d_in[5];
    const float* n2b    = (const float*)d_in[6];
    const float* Wv     = (const float*)d_in[7];
    const float* bv     = (const float*)d_in[8];
    const float* Ww     = (const float*)d_in[9];
    const float* bw     = (const float*)d_in[10];
    const float* Wk     = (const float*)d_in[11];
    const float* bk     = (const float*)d_in[12];
    const float* Wo     = (const float*)d_in[13];
    const float* bo     = (const float*)d_in[14];

    float* out = (float*)d_out;
    float* kp  = out + (size_t)B * C * HW;                       // kp tail of d_out
    float* wts = (float*)d_ws;                                   // fp32, 18.9 MB
    __hip_bfloat16* val = (__hip_bfloat16*)((char*)d_ws + VAL_OFF_BYTES);  // bf16, 33.6 MB

    dim3 grid(NBLK), block(256);
    k1_ln1_proj<<<grid, block, 0, stream>>>(feats1, anchor, n1g, n1b, Ww, bw, Wk, bk, wts, kp);
    k2_ln2_value<<<grid, block, 0, stream>>>(feats2, n2g, n2b, Wv, bv, val);
    k3_gather_out<<<grid, block, 0, stream>>>(wts, kp, val, Wo, bo, out);
}

// Round 2
// 457.424 us; speedup vs baseline: 4.4158x; 4.4158x over previous
//
#include <hip/hip_runtime.h>
#include <hip/hip_bf16.h>

// Deformable1DFeatureAggregator on MI355X (gfx950) — round 1
// Pipeline (7 kernels):
//   prep   : transpose Ww/Wv/Wo -> bf16 N x K layouts (ws)
//   k1_ln1 : LN(feats1) -> x1b bf16 (ws R1); fp32 Wk offsets -> kp (d_out tail)
//   gemmW  : logits = x1b @ WwT^T (MFMA) + softmax over P -> wts fp32 (ws R3)
//   k2_ln2 : LN(feats2) -> x2b bf16 (ws R1, after gemmW consumed x1b)
//   gemmV  : value = x2b @ WvT^T (MFMA) + bv -> val bf16 (ws R2)
//   gather : vectorized bilinear gather (uint2 = 4ch/lane) -> aggb bf16 (ws R1)
//   gemmO  : out = aggb @ WoT^T (MFMA) + bo -> out fp32 (b,c,h,w)
//
// ws layout (bytes):
//   [0, 33554432)           R1: x1b / x2b / aggb  (65536 x 256 bf16)
//   [33554432, 67108864)    R2: val               (65536 x 256 bf16)
//   [67108864, 85983232)    R3: wts fp32          (65536 x 72, layout [pix][g*9+p])
//   [85983232, 86286336)    weights: WwT(80x256) WvT(256x256) WoT(256x256) bf16

constexpr int B = 2, C = 256, H = 128, W = 256;
constexpr int HW = H * W;            // 32768
constexpr int P = 9, G = 8;
constexpr int PIX = 32;
constexpr int NPIX = B * HW;         // 65536

typedef __attribute__((ext_vector_type(8))) __bf16 bf16x8;
typedef __attribute__((ext_vector_type(4))) float f32x4;

static __device__ __forceinline__ unsigned short f2bf(float x) {
    __hip_bfloat16 h = __float2bfloat16(x);
    return *reinterpret_cast<unsigned short*>(&h);
}
static __device__ __forceinline__ unsigned int pack2(float a, float b) {
    return (unsigned int)f2bf(a) | ((unsigned int)f2bf(b) << 16);
}
static __device__ __forceinline__ bf16x8 ldb8(const unsigned short* p) {
    return *reinterpret_cast<const bf16x8*>(p);
}

// ---------------------------------------------------------------------------
// prep: fp32 K x N weights -> bf16 N x K  (WwT padded to 80 rows with zeros)
// ---------------------------------------------------------------------------
__global__ __launch_bounds__(256) void k_prep(
    const float* __restrict__ Ww, const float* __restrict__ Wv,
    const float* __restrict__ Wo,
    unsigned short* __restrict__ WwT, unsigned short* __restrict__ WvT,
    unsigned short* __restrict__ WoT)
{
    int tid = blockIdx.x * 256 + threadIdx.x;   // 592 blocks -> 151552 threads
    if (tid < 20480) {
        int n = tid >> 8, k = tid & 255;
        float v = (n < 72) ? Ww[k * 72 + n] : 0.f;
        WwT[tid] = f2bf(v);
    } else if (tid < 20480 + 65536) {
        int i = tid - 20480;
        int n = i >> 8, k = i & 255;
        WvT[i] = f2bf(Wv[k * 256 + n]);
    } else {
        int i = tid - 86016;
        int n = i >> 8, k = i & 255;
        WoT[i] = f2bf(Wo[k * 256 + n]);
    }
}

// ---------------------------------------------------------------------------
// k1_ln1: LN(feats1) -> x1b bf16; fp32 offsets via Wk -> kp
// ---------------------------------------------------------------------------
__global__ __launch_bounds__(256) void k1_ln1(
    const float* __restrict__ feats1,
    const float* __restrict__ anchor,
    const float* __restrict__ g1, const float* __restrict__ b1,
    const float* __restrict__ Wk, const float* __restrict__ bk,
    unsigned short* __restrict__ x1b, float* __restrict__ kp_out)
{
    __shared__ float X[PIX][C + 1];
    __shared__ float red[2][8][PIX];
    __shared__ float meanA[PIX], rstdA[PIX];

    const int t = threadIdx.x;
    const int p = t & 31;
    const int part = t >> 5;
    const int gpix0 = blockIdx.x * PIX;
    const int b = gpix0 >> 15;
    const int n0 = gpix0 & (HW - 1);
    const float* Fb = feats1 + (size_t)b * C * HW;

    #pragma unroll
    for (int i = 0; i < 32; ++i) {
        int c = i * 8 + part;
        X[p][c] = Fb[(size_t)c * HW + n0 + p];
    }
    __syncthreads();

    float s = 0.f, ss = 0.f;
    #pragma unroll
    for (int i = 0; i < 32; ++i) {
        float v = X[p][part * 32 + i];
        s += v; ss += v * v;
    }
    red[0][part][p] = s; red[1][part][p] = ss;
    __syncthreads();
    if (part == 0) {
        float s2 = 0.f, ss2 = 0.f;
        #pragma unroll
        for (int k = 0; k < 8; ++k) { s2 += red[0][k][p]; ss2 += red[1][k][p]; }
        float mean = s2 * (1.f / C);
        float var  = ss2 * (1.f / C) - mean * mean;
        meanA[p] = mean; rstdA[p] = rsqrtf(var + 1e-5f);
    }
    __syncthreads();
    {
        float mean = meanA[p], rstd = rstdA[p];
        #pragma unroll
        for (int i = 0; i < 32; ++i) {
            int c = part * 32 + i;
            X[p][c] = (X[p][c] - mean) * rstd * g1[c] + b1[c];
        }
    }
    __syncthreads();

    // write x1b bf16 (pix-major)
    {
        unsigned short* row = x1b + ((size_t)gpix0 + p) * C + part * 32;
        #pragma unroll
        for (int i4 = 0; i4 < 8; ++i4) {
            uint2 u;
            u.x = pack2(X[p][part * 32 + i4 * 4 + 0], X[p][part * 32 + i4 * 4 + 1]);
            u.y = pack2(X[p][part * 32 + i4 * 4 + 2], X[p][part * 32 + i4 * 4 + 3]);
            *reinterpret_cast<uint2*>(row + i4 * 4) = u;
        }
    }

    // fp32 offsets (exactness matters: feeds bilinear sample positions)
    const size_t pixg = (size_t)gpix0 + p;
    const float ax = anchor[pixg * 2 + 0];
    const float ay = anchor[pixg * 2 + 1];
    for (int j = 72 + part; j < 81; j += 8) {
        int pt = j - 72;
        float acc = bk[pt];
        #pragma unroll 4
        for (int c = 0; c < C; ++c) acc += X[p][c] * Wk[c * P + pt];
        size_t o = (pixg * P + pt) * 2;
        kp_out[o] = ax + acc;
        kp_out[o + 1] = ay;
    }
}

// ---------------------------------------------------------------------------
// k2_ln2: LN(feats2) -> x2b bf16
// ---------------------------------------------------------------------------
__global__ __launch_bounds__(256) void k2_ln2(
    const float* __restrict__ feats2,
    const float* __restrict__ g2, const float* __restrict__ b2,
    unsigned short* __restrict__ x2b)
{
    __shared__ float X[PIX][C + 1];
    __shared__ float red[2][8][PIX];
    __shared__ float meanA[PIX], rstdA[PIX];

    const int t = threadIdx.x;
    const int p = t & 31;
    const int part = t >> 5;
    const int gpix0 = blockIdx.x * PIX;
    const int b = gpix0 >> 15;
    const int n0 = gpix0 & (HW - 1);
    const float* Fb = feats2 + (size_t)b * C * HW;

    #pragma unroll
    for (int i = 0; i < 32; ++i) {
        int c = i * 8 + part;
        X[p][c] = Fb[(size_t)c * HW + n0 + p];
    }
    __syncthreads();

    float s = 0.f, ss = 0.f;
    #pragma unroll
    for (int i = 0; i < 32; ++i) {
        float v = X[p][part * 32 + i];
        s += v; ss += v * v;
    }
    red[0][part][p] = s; red[1][part][p] = ss;
    __syncthreads();
    if (part == 0) {
        float s2 = 0.f, ss2 = 0.f;
        #pragma unroll
        for (int k = 0; k < 8; ++k) { s2 += red[0][k][p]; ss2 += red[1][k][p]; }
        float mean = s2 * (1.f / C);
        float var  = ss2 * (1.f / C) - mean * mean;
        meanA[p] = mean; rstdA[p] = rsqrtf(var + 1e-5f);
    }
    __syncthreads();
    {
        float mean = meanA[p], rstd = rstdA[p];
        unsigned short* row = x2b + ((size_t)gpix0 + p) * C + part * 32;
        #pragma unroll
        for (int i4 = 0; i4 < 8; ++i4) {
            float v0 = (X[p][part * 32 + i4 * 4 + 0] - mean) * rstd * g2[part * 32 + i4 * 4 + 0] + b2[part * 32 + i4 * 4 + 0];
            float v1 = (X[p][part * 32 + i4 * 4 + 1] - mean) * rstd * g2[part * 32 + i4 * 4 + 1] + b2[part * 32 + i4 * 4 + 1];
            float v2 = (X[p][part * 32 + i4 * 4 + 2] - mean) * rstd * g2[part * 32 + i4 * 4 + 2] + b2[part * 32 + i4 * 4 + 2];
            float v3 = (X[p][part * 32 + i4 * 4 + 3] - mean) * rstd * g2[part * 32 + i4 * 4 + 3] + b2[part * 32 + i4 * 4 + 3];
            uint2 u; u.x = pack2(v0, v1); u.y = pack2(v2, v3);
            *reinterpret_cast<uint2*>(row + i4 * 4) = u;
        }
    }
}

// ---------------------------------------------------------------------------
// gemmW: logits = x1b(65536x256) @ Ww(256x72) via MFMA; softmax over P
// block: 128 pixels; wave: 32 pixels x 80 cols. wts layout [pix][g*9+p] fp32.
// ---------------------------------------------------------------------------
__global__ __launch_bounds__(256) void k_gemmw(
    const unsigned short* __restrict__ x1b,
    const unsigned short* __restrict__ WwT,
    const float* __restrict__ bw,
    float* __restrict__ wts)
{
    __shared__ float L[128][81];

    const int t = threadIdx.x;
    const int wave = t >> 6, lane = t & 63;
    const int m_base = blockIdx.x * 128;
    const int m0 = m_base + wave * 32;
    const int l15 = lane & 15, quad = lane >> 4;

    f32x4 acc[2][5];
    #pragma unroll
    for (int ms = 0; ms < 2; ++ms)
        #pragma unroll
        for (int ns = 0; ns < 5; ++ns)
            acc[ms][ns] = (f32x4){0.f, 0.f, 0.f, 0.f};

    size_t aoff[2], boff[5];
    #pragma unroll
    for (int ms = 0; ms < 2; ++ms)
        aoff[ms] = (size_t)(m0 + ms * 16 + l15) * 256 + quad * 8;
    #pragma unroll
    for (int ns = 0; ns < 5; ++ns)
        boff[ns] = (size_t)(ns * 16 + l15) * 256 + quad * 8;

    for (int kk = 0; kk < 8; ++kk) {
        bf16x8 a[2], bfr[5];
        #pragma unroll
        for (int ms = 0; ms < 2; ++ms) a[ms] = ldb8(x1b + aoff[ms] + kk * 32);
        #pragma unroll
        for (int ns = 0; ns < 5; ++ns) bfr[ns] = ldb8(WwT + boff[ns] + kk * 32);
        #pragma unroll
        for (int ms = 0; ms < 2; ++ms)
            #pragma unroll
            for (int ns = 0; ns < 5; ++ns)
                acc[ms][ns] = __builtin_amdgcn_mfma_f32_16x16x32_bf16(a[ms], bfr[ns], acc[ms][ns], 0, 0, 0);
    }

    // bias + stage logits to LDS
    float bias[5];
    #pragma unroll
    for (int ns = 0; ns < 5; ++ns) {
        int n = ns * 16 + l15;
        bias[ns] = (n < 72) ? bw[n] : 0.f;
    }
    #pragma unroll
    for (int ms = 0; ms < 2; ++ms) {
        #pragma unroll
        for (int ns = 0; ns < 5; ++ns) {
            int n = ns * 16 + l15;
            if (n < 72) {
                #pragma unroll
                for (int r = 0; r < 4; ++r) {
                    int ml = wave * 32 + ms * 16 + quad * 4 + r;
                    L[ml][n] = acc[ms][ns][r] + bias[ns];
                }
            }
        }
    }
    __syncthreads();

    // softmax over P (cols {g, g+8, ..., g+64}); write wts [pix][g*9+p]
    for (int tau = t; tau < 1024; tau += 256) {
        int px = tau >> 3, g = tau & 7;
        float m = -1e30f;
        #pragma unroll
        for (int pt = 0; pt < P; ++pt) m = fmaxf(m, L[px][pt * 8 + g]);
        float e[P], sum = 0.f;
        #pragma unroll
        for (int pt = 0; pt < P; ++pt) { e[pt] = __expf(L[px][pt * 8 + g] - m); sum += e[pt]; }
        float inv = 1.f / sum;
        float* wb = wts + (size_t)(m_base + px) * 72 + g * 9;
        #pragma unroll
        for (int pt = 0; pt < P; ++pt) wb[pt] = e[pt] * inv;
    }
}

// ---------------------------------------------------------------------------
// gemmV: val = x2b @ Wv + bv (MFMA), bf16 out pix-major.
// block: 64 pixels x 256 cols; wave: 64 pixels x 64 cols.
// ---------------------------------------------------------------------------
__global__ __launch_bounds__(256) void k_gemmv(
    const unsigned short* __restrict__ x2b,
    const unsigned short* __restrict__ WvT,
    const float* __restrict__ bv,
    unsigned short* __restrict__ val)
{
    const int t = threadIdx.x;
    const int wave = t >> 6, lane = t & 63;
    const int m_base = blockIdx.x * 64;
    const int n0 = wave * 64;
    const int l15 = lane & 15, quad = lane >> 4;

    f32x4 acc[4][4];
    #pragma unroll
    for (int ms = 0; ms < 4; ++ms)
        #pragma unroll
        for (int ns = 0; ns < 4; ++ns)
            acc[ms][ns] = (f32x4){0.f, 0.f, 0.f, 0.f};

    size_t aoff[4], boff[4];
    #pragma unroll
    for (int ms = 0; ms < 4; ++ms)
        aoff[ms] = (size_t)(m_base + ms * 16 + l15) * 256 + quad * 8;
    #pragma unroll
    for (int ns = 0; ns < 4; ++ns)
        boff[ns] = (size_t)(n0 + ns * 16 + l15) * 256 + quad * 8;

    for (int kk = 0; kk < 8; ++kk) {
        bf16x8 a[4], bfr[4];
        #pragma unroll
        for (int ms = 0; ms < 4; ++ms) a[ms] = ldb8(x2b + aoff[ms] + kk * 32);
        #pragma unroll
        for (int ns = 0; ns < 4; ++ns) bfr[ns] = ldb8(WvT + boff[ns] + kk * 32);
        #pragma unroll
        for (int ms = 0; ms < 4; ++ms)
            #pragma unroll
            for (int ns = 0; ns < 4; ++ns)
                acc[ms][ns] = __builtin_amdgcn_mfma_f32_16x16x32_bf16(a[ms], bfr[ns], acc[ms][ns], 0, 0, 0);
    }

    float bvr[4];
    #pragma unroll
    for (int ns = 0; ns < 4; ++ns) bvr[ns] = bv[n0 + ns * 16 + l15];

    #pragma unroll
    for (int ms = 0; ms < 4; ++ms) {
        #pragma unroll
        for (int ns = 0; ns < 4; ++ns) {
            int n = n0 + ns * 16 + l15;
            #pragma unroll
            for (int r = 0; r < 4; ++r) {
                int pix = m_base + ms * 16 + quad * 4 + r;
                val[(size_t)pix * 256 + n] = f2bf(acc[ms][ns][r] + bvr[ns]);
            }
        }
    }
}

// ---------------------------------------------------------------------------
// gather: vectorized bilinear gather + group-weighted point sum -> aggb bf16
// lane covers channels [4*lane, 4*lane+4); wave processes 8 pixels.
// ---------------------------------------------------------------------------
__global__ __launch_bounds__(256) void k_gather(
    const float* __restrict__ wts,
    const float* __restrict__ kp,
    const unsigned short* __restrict__ val,
    unsigned short* __restrict__ aggb)
{
    __shared__ float Wl[PIX][72];
    __shared__ float KPl[PIX][18];

    const int t = threadIdx.x;
    const int gpix0 = blockIdx.x * PIX;
    const int b = gpix0 >> 15;

    for (int f = t; f < PIX * 72; f += 256)
        ((float*)Wl)[f] = wts[(size_t)gpix0 * 72 + f];
    for (int f = t; f < PIX * 18; f += 256)
        ((float*)KPl)[f] = kp[(size_t)gpix0 * 18 + f];
    __syncthreads();

    const int wave = t >> 6, lane = t & 63;
    const int gl = lane >> 3;                      // channel group
    const unsigned short* vbp = val + (size_t)b * HW * 256 + 4 * lane;

    for (int px = wave; px < PIX; px += 4) {
        const float ay = KPl[px][1];
        float yf = ay * (float)H - 0.5f;
        float y0f = floorf(yf);
        float wy = yf - y0f;
        int y0 = (int)y0f;
        float vy0 = ((unsigned)y0 < (unsigned)H) ? 1.f : 0.f;
        float vy1 = ((unsigned)(y0 + 1) < (unsigned)H) ? 1.f : 0.f;
        int y0c = min(max(y0, 0), H - 1);
        int y1c = min(max(y0 + 1, 0), H - 1);

        float a0 = 0.f, a1 = 0.f, a2 = 0.f, a3 = 0.f;

        #pragma unroll
        for (int pt = 0; pt < P; ++pt) {
            float kx = KPl[px][2 * pt];
            float w  = Wl[px][gl * 9 + pt];
            float xf = kx * (float)W - 0.5f;
            float x0f = floorf(xf);
            float wx = xf - x0f;
            int x0 = (int)x0f;
            float vx0 = ((unsigned)x0 < (unsigned)W) ? 1.f : 0.f;
            float vx1 = ((unsigned)(x0 + 1) < (unsigned)W) ? 1.f : 0.f;
            int x0c = min(max(x0, 0), W - 1);
            int x1c = min(max(x0 + 1, 0), W - 1);

            float c00 = w * (1.f - wx) * (1.f - wy) * vy0 * vx0;
            float c01 = w * wx * (1.f - wy) * vy0 * vx1;
            float c10 = w * (1.f - wx) * wy * vy1 * vx0;
            float c11 = w * wx * wy * vy1 * vx1;

            uint2 u00 = *(const uint2*)(vbp + ((size_t)(y0c * W + x0c) << 8));
            uint2 u01 = *(const uint2*)(vbp + ((size_t)(y0c * W + x1c) << 8));
            uint2 u10 = *(const uint2*)(vbp + ((size_t)(y1c * W + x0c) << 8));
            uint2 u11 = *(const uint2*)(vbp + ((size_t)(y1c * W + x1c) << 8));

            a0 += c00 * __uint_as_float(u00.x << 16) + c01 * __uint_as_float(u01.x << 16)
                + c10 * __uint_as_float(u10.x << 16) + c11 * __uint_as_float(u11.x << 16);
            a1 += c00 * __uint_as_float(u00.x & 0xffff0000u) + c01 * __uint_as_float(u01.x & 0xffff0000u)
                + c10 * __uint_as_float(u10.x & 0xffff0000u) + c11 * __uint_as_float(u11.x & 0xffff0000u);
            a2 += c00 * __uint_as_float(u00.y << 16) + c01 * __uint_as_float(u01.y << 16)
                + c10 * __uint_as_float(u10.y << 16) + c11 * __uint_as_float(u11.y << 16);
            a3 += c00 * __uint_as_float(u00.y & 0xffff0000u) + c01 * __uint_as_float(u01.y & 0xffff0000u)
                + c10 * __uint_as_float(u10.y & 0xffff0000u) + c11 * __uint_as_float(u11.y & 0xffff0000u);
        }

        uint2 o;
        o.x = pack2(a0, a1);
        o.y = pack2(a2, a3);
        *reinterpret_cast<uint2*>(aggb + ((size_t)(gpix0 + px) << 8) + 4 * lane) = o;
    }
}

// ---------------------------------------------------------------------------
// gemmO: out = aggb @ Wo + bo (MFMA), fp32 out in (b,c,hw) layout.
// block: 64 pixels (N) x 256 out-channels (M); wave: 64 ch x 64 pix.
// ---------------------------------------------------------------------------
__global__ __launch_bounds__(256) void k_gemmo(
    const unsigned short* __restrict__ aggb,
    const unsigned short* __restrict__ WoT,
    const float* __restrict__ bo,
    float* __restrict__ out)
{
    const int t = threadIdx.x;
    const int wave = t >> 6, lane = t & 63;
    const int n_base = blockIdx.x * 64;            // pixel base
    const int b = n_base >> 15;
    const int hw0 = n_base & (HW - 1);
    const int m0 = wave * 64;                      // out-channel base
    const int l15 = lane & 15, quad = lane >> 4;

    f32x4 acc[4][4];
    #pragma unroll
    for (int ms = 0; ms < 4; ++ms)
        #pragma unroll
        for (int ns = 0; ns < 4; ++ns)
            acc[ms][ns] = (f32x4){0.f, 0.f, 0.f, 0.f};

    size_t aoff[4], boff[4];
    #pragma unroll
    for (int ms = 0; ms < 4; ++ms)
        aoff[ms] = (size_t)(m0 + ms * 16 + l15) * 256 + quad * 8;
    #pragma unroll
    for (int ns = 0; ns < 4; ++ns)
        boff[ns] = (size_t)(n_base + ns * 16 + l15) * 256 + quad * 8;

    for (int kk = 0; kk < 8; ++kk) {
        bf16x8 a[4], bfr[4];
        #pragma unroll
        for (int ms = 0; ms < 4; ++ms) a[ms] = ldb8(WoT + aoff[ms] + kk * 32);
        #pragma unroll
        for (int ns = 0; ns < 4; ++ns) bfr[ns] = ldb8(aggb + boff[ns] + kk * 32);
        #pragma unroll
        for (int ms = 0; ms < 4; ++ms)
            #pragma unroll
            for (int ns = 0; ns < 4; ++ns)
                acc[ms][ns] = __builtin_amdgcn_mfma_f32_16x16x32_bf16(a[ms], bfr[ns], acc[ms][ns], 0, 0, 0);
    }

    float bor[4][4];
    #pragma unroll
    for (int ms = 0; ms < 4; ++ms)
        #pragma unroll
        for (int r = 0; r < 4; ++r)
            bor[ms][r] = bo[m0 + ms * 16 + quad * 4 + r];

    #pragma unroll
    for (int ms = 0; ms < 4; ++ms) {
        #pragma unroll
        for (int ns = 0; ns < 4; ++ns) {
            #pragma unroll
            for (int r = 0; r < 4; ++r) {
                int ch = m0 + ms * 16 + quad * 4 + r;
                int pixn = ns * 16 + l15;
                out[((size_t)b * 256 + ch) * HW + hw0 + pixn] = acc[ms][ns][r] + bor[ms][r];
            }
        }
    }
}

// ---------------------------------------------------------------------------
extern "C" void kernel_launch(void* const* d_in, const int* in_sizes, int n_in,
                              void* d_out, int out_size, void* d_ws, size_t ws_size,
                              hipStream_t stream)
{
    const float* feats1 = (const float*)d_in[0];
    const float* feats2 = (const float*)d_in[1];
    const float* anchor = (const float*)d_in[2];
    const float* n1g    = (const float*)d_in[3];
    const float* n1b    = (const float*)d_in[4];
    const float* n2g    = (const float*)d_in[5];
    const float* n2b    = (const float*)d_in[6];
    const float* Wv     = (const float*)d_in[7];
    const float* bv     = (const float*)d_in[8];
    const float* Ww     = (const float*)d_in[9];
    const float* bw     = (const float*)d_in[10];
    const float* Wk     = (const float*)d_in[11];
    const float* bk     = (const float*)d_in[12];
    const float* Wo     = (const float*)d_in[13];
    const float* bo     = (const float*)d_in[14];

    float* out = (float*)d_out;
    float* kp  = out + (size_t)B * C * HW;

    unsigned short* R1  = (unsigned short*)d_ws;                          // x1b / x2b / aggb
    unsigned short* val = (unsigned short*)((char*)d_ws + 33554432);      // R2
    float*          wts = (float*)((char*)d_ws + 67108864);               // R3
    unsigned short* WwT = (unsigned short*)((char*)d_ws + 85983232);
    unsigned short* WvT = WwT + 20480;
    unsigned short* WoT = WvT + 65536;

    k_prep <<<592,  256, 0, stream>>>(Ww, Wv, Wo, WwT, WvT, WoT);
    k1_ln1 <<<2048, 256, 0, stream>>>(feats1, anchor, n1g, n1b, Wk, bk, R1, kp);
    k_gemmw<<<512,  256, 0, stream>>>(R1, WwT, bw, wts);
    k2_ln2 <<<2048, 256, 0, stream>>>(feats2, n2g, n2b, R1);              // R1 now x2b
    k_gemmv<<<1024, 256, 0, stream>>>(R1, WvT, bv, val);
    k_gather<<<2048,256, 0, stream>>>(wts, kp, val, R1);                  // R1 now aggb
    k_gemmo<<<1024, 256, 0, stream>>>(R1, WoT, bo, out);
}